// Round 3
// baseline (261.551 us; speedup 1.0000x reference)
//
#include <hip/hip_runtime.h>
#include <stdint.h>

typedef unsigned short u16;
typedef __attribute__((ext_vector_type(8))) short short8;   // 8 bf16 in 4 VGPRs
typedef __attribute__((ext_vector_type(4))) float f32x4;

// ---------- bf16 helpers ----------
__device__ __forceinline__ float bf2f(u16 u) {
    union { unsigned u; float f; } x; x.u = ((unsigned)u) << 16; return x.f;
}
__device__ __forceinline__ float bf_lo(unsigned w) {
    union { unsigned u; float f; } x; x.u = w << 16; return x.f;
}
__device__ __forceinline__ float bf_hi(unsigned w) {
    union { unsigned u; float f; } x; x.u = w & 0xffff0000u; return x.f;
}
__device__ __forceinline__ u16 f2bf(float f) {   // round-to-nearest-even
    union { float f; unsigned u; } x; x.f = f;
    unsigned r = x.u + 0x7fffu + ((x.u >> 16) & 1u);
    return (u16)(r >> 16);
}
__device__ __forceinline__ uint4 cvt8(const float* p) {
    float4 a = *reinterpret_cast<const float4*>(p);
    float4 b = *reinterpret_cast<const float4*>(p + 4);
    uint4 r;
    r.x = (unsigned)f2bf(a.x) | ((unsigned)f2bf(a.y) << 16);
    r.y = (unsigned)f2bf(a.z) | ((unsigned)f2bf(a.w) << 16);
    r.z = (unsigned)f2bf(b.x) | ((unsigned)f2bf(b.y) << 16);
    r.w = (unsigned)f2bf(b.z) | ((unsigned)f2bf(b.w) << 16);
    return r;
}

// async global -> LDS, 16 bytes per lane (lds dest = wave-uniform base + lane*16)
__device__ __forceinline__ void gl16(const u16* g, u16* l) {
    __builtin_amdgcn_global_load_lds(
        (const __attribute__((address_space(1))) void*)g,
        (__attribute__((address_space(3))) void*)l, 16, 0, 0);
}

// ---------- fp32 -> bf16 bulk converts ----------
__global__ __launch_bounds__(256) void cvt_kernel(const float* __restrict__ in,
                                                  u16* __restrict__ out, int n8) {
    int i = blockIdx.x * 256 + threadIdx.x;
    if (i < n8) *reinterpret_cast<uint4*>(&out[(size_t)i * 8]) = cvt8(&in[(size_t)i * 8]);
}

// fused 3-array convert into one contiguous bf16 region
__global__ __launch_bounds__(256) void cvt3_kernel(const float* __restrict__ a, int na8,
                                                   const float* __restrict__ b, int nb8,
                                                   const float* __restrict__ c, int nc8,
                                                   u16* __restrict__ dst) {
    int i = blockIdx.x * 256 + threadIdx.x;
    const float* src; int off;
    if (i < na8)            { src = a; off = i; }
    else if (i < na8 + nb8) { src = b; off = i - na8; }
    else if (i < na8 + nb8 + nc8) { src = c; off = i - na8 - nb8; }
    else return;
    *reinterpret_cast<uint4*>(&dst[(size_t)i * 8]) = cvt8(&src[(size_t)off * 8]);
}

#define BM 128
#define BN 128
#define BK 32
#define BKA 64

// ============================================================
// R8: m201-faithful 256x256 8-phase GEMM (T2+T3+T4+T5).
// 512 thr = 8 waves (2M x 4N), per-wave 128x64 out = acc[8][4].
// LDS: As[2][256*64] + Ws[2][256*64] = 128 KB, double-buffered by K-tile.
// Per K-tile t (buf cb=t&1), 4 phases:
//   p0: ds_read B-all(8)+A-sub0(4); stage A1,A3(t+1)->As[cb^1]; bar;
//       lgkm0; 16 MFMA; bar.
//   p1: ds_read A-sub1(4); stage W0,W1(t+2)->Ws[cb]; ...
//   p2: ds_read A-sub2(4); stage W2,W3(t+2)->Ws[cb]; ...
//   p3: ds_read A-sub3(4); stage A0,A2(t+2)->As[cb]; vmcnt(6); bar;
//       lgkm0; 16 MFMA; bar.
// Stage targets = exactly the units freed by the previous phase's closing
// barrier (Ws fully read in p0; A-units 0,2 read after p1; 1,3 after p3).
// vmcnt(6) in p3 (in-order retirement) => ALL of tile t+1's 8 loads landed,
// 6 newest (tile t+2's W+A02) may remain in flight; p3's closing barrier
// publishes. Never vmcnt(0) in the loop; tail vmcnt(0) for LDS reuse safety.
// B-frags (8 short8) loaded once per K-tile, reused across all 4 phases:
// 4 ds_read per 16 MFMA in p1-p3 (m201 ratio), 12 in p0.
// ============================================================
#define PBK 64

template<bool CF32>
__global__ __launch_bounds__(512, 2) void gemm256(const u16* __restrict__ A,
                                                  const u16* __restrict__ W,
                                                  void* __restrict__ Cv,
                                                  const float* __restrict__ bias,
                                                  int M, int N, int K, int lda,
                                                  u16* __restrict__ vt) {
    __shared__ __align__(16) u16 As[2][256 * PBK];   // 2 x 32 KB
    __shared__ __align__(16) u16 Ws[2][256 * PBK];   // 2 x 32 KB

    const int tid  = threadIdx.x;
    const int lane = tid & 63;
    const int w    = tid >> 6;      // 0..7
    const int wm   = w >> 2;        // 0..1  (M half)
    const int wn   = w & 3;         // 0..3  (N quarter)
    const int quad = lane >> 4;
    const int l16  = lane & 15;
    const int ro   = l16 & 7;

    const int row0 = blockIdx.y * 256;
    const int col0 = blockIdx.x * 256;

    // staging: one gl16/thread covers one 64-row "unit": row = q*64 + w*8 +
    // (lane>>3), chunk gc = (lane&7)^(lane>>3); LDS linear => LDS slot s of
    // row r holds global chunk s ^ (r&7)  (same swizzle as gemm_bt_a, 0-conflict).
    const int srow = w * 8 + (lane >> 3);
    const int gc   = (lane & 7) ^ (lane >> 3);
    const int lub  = (w * 8) * PBK;              // + q*64*PBK per unit

    const u16* gA[4]; const u16* gW[4];
#pragma unroll
    for (int q = 0; q < 4; q++) {
        gA[q] = A + (size_t)(row0 + q * 64 + srow) * lda + gc * 8;
        gW[q] = W + (size_t)(col0 + q * 64 + srow) * K  + gc * 8;
    }

    f32x4 acc[8][4] = {};

    const int NT = K / PBK;   // 16 for K=1024

    // ---- prologue: tile0 all 8 units, then tile1 W0-3, A0, A2 (6 units) ----
#pragma unroll
    for (int q = 0; q < 4; q++) gl16(gA[q], &As[0][q * 64 * PBK + lub]);
#pragma unroll
    for (int q = 0; q < 4; q++) gl16(gW[q], &Ws[0][q * 64 * PBK + lub]);
#pragma unroll
    for (int q = 0; q < 4; q++) gl16(gW[q] + PBK, &Ws[1][q * 64 * PBK + lub]);
    gl16(gA[0] + PBK, &As[1][0 * 64 * PBK + lub]);
    gl16(gA[2] + PBK, &As[1][2 * 64 * PBK + lub]);
    asm volatile("s_waitcnt vmcnt(6)" ::: "memory");   // tile0's 8 landed
    __builtin_amdgcn_s_barrier();

#define READ_A(P)                                                              \
    _Pragma("unroll") for (int im = 0; im < 2; im++)                           \
    _Pragma("unroll") for (int ks = 0; ks < 2; ks++)                           \
        af[im][ks] = *reinterpret_cast<const short8*>(                         \
            &As[cb][(wm * 128 + (P) * 32 + im * 16 + l16) * PBK +              \
                    (((ks * 4 + quad) ^ ro) * 8)]);

#define PHASE_TAIL(IB)                                                         \
    __builtin_amdgcn_s_barrier();                                              \
    asm volatile("s_waitcnt lgkmcnt(0)" ::: "memory");                         \
    __builtin_amdgcn_s_setprio(1);                                             \
    _Pragma("unroll") for (int ks = 0; ks < 2; ks++)                           \
    _Pragma("unroll") for (int im = 0; im < 2; im++)                           \
    _Pragma("unroll") for (int jn = 0; jn < 4; jn++)                           \
        acc[(IB) + im][jn] = __builtin_amdgcn_mfma_f32_16x16x32_bf16(          \
            af[im][ks], bf[jn][ks], acc[(IB) + im][jn], 0, 0, 0);              \
    __builtin_amdgcn_s_setprio(0);                                             \
    __builtin_amdgcn_s_barrier();

    for (int t = 0; t < NT; t++) {
        const int cb = t & 1;
        const int kA = (t + 1 < NT ? t + 1 : NT - 1) * PBK;   // tile t+1 (A1,A3)
        const int k2 = (t + 2 < NT ? t + 2 : NT - 1) * PBK;   // tile t+2

        short8 bf[4][2], af[2][2];

        // ---------------- phase 0 ----------------
#pragma unroll
        for (int jn = 0; jn < 4; jn++)
#pragma unroll
            for (int ks = 0; ks < 2; ks++)
                bf[jn][ks] = *reinterpret_cast<const short8*>(
                    &Ws[cb][(wn * 64 + jn * 16 + l16) * PBK + (((ks * 4 + quad) ^ ro) * 8)]);
        READ_A(0)
        gl16(gA[1] + kA, &As[cb ^ 1][1 * 64 * PBK + lub]);
        gl16(gA[3] + kA, &As[cb ^ 1][3 * 64 * PBK + lub]);
        PHASE_TAIL(0)

        // ---------------- phase 1 ----------------
        READ_A(1)
        gl16(gW[0] + k2, &Ws[cb][0 * 64 * PBK + lub]);
        gl16(gW[1] + k2, &Ws[cb][1 * 64 * PBK + lub]);
        PHASE_TAIL(2)

        // ---------------- phase 2 ----------------
        READ_A(2)
        gl16(gW[2] + k2, &Ws[cb][2 * 64 * PBK + lub]);
        gl16(gW[3] + k2, &Ws[cb][3 * 64 * PBK + lub]);
        PHASE_TAIL(4)

        // ---------------- phase 3 ----------------
        READ_A(3)
        gl16(gA[0] + k2, &As[cb][0 * 64 * PBK + lub]);
        gl16(gA[2] + k2, &As[cb][2 * 64 * PBK + lub]);
        asm volatile("s_waitcnt vmcnt(6)" ::: "memory");  // tile t+1 fully landed
        PHASE_TAIL(6)
    }
#undef READ_A
#undef PHASE_TAIL
    // drain in-flight DMA: next block on this CU reuses our LDS
    asm volatile("s_waitcnt vmcnt(0)" ::: "memory");

    // epilogue: C/D layout col=lane&15, row=quad*4+reg  [verified m89/m91]
    if (vt != nullptr && col0 >= 2048) {
        // fused V-transpose: 4 consecutive t per lane -> one 8B store
        const int b = row0 >> 10;
#pragma unroll
        for (int jn = 0; jn < 4; jn++) {
            const int hd = col0 - 2048 + wn * 64 + jn * 16 + l16;   // h*64+dh
            u16* dstc = vt + (size_t)(b * 1024 + hd) * 1024 + (row0 & 1023) + wm * 128;
#pragma unroll
            for (int i = 0; i < 8; i++) {
                const int t0 = i * 16 + quad * 4;
                u16 pk[4];
#pragma unroll
                for (int r = 0; r < 4; r++) pk[r] = f2bf(acc[i][jn][r]);
                *reinterpret_cast<uint2*>(dstc + t0) = *reinterpret_cast<uint2*>(pk);
            }
        }
    } else {
#pragma unroll
        for (int jn = 0; jn < 4; jn++) {
            const int col = col0 + wn * 64 + jn * 16 + l16;
            const float bval = bias ? bias[col] : 0.0f;
#pragma unroll
            for (int i = 0; i < 8; i++) {
#pragma unroll
                for (int r = 0; r < 4; r++) {
                    const int row = row0 + wm * 128 + i * 16 + quad * 4 + r;
                    if (CF32) ((float*)Cv)[(size_t)row * N + col] = acc[i][jn][r] + bval;
                    else      ((u16*)Cv)[(size_t)row * N + col]  = f2bf(acc[i][jn][r] + bval);
                }
            }
        }
    }
}

// ============================================================
// m97-class GEMM, BK=64, SINGLE-buffered (R4/R6 structure) — known-good:
// 68.5 µs / 752 TF on QKV shape, used for proj (better grid: 512 blocks).
// ============================================================
template<bool CF32>
__global__ __launch_bounds__(256) void gemm_bt_a(const u16* __restrict__ A,
                                                 const u16* __restrict__ W,
                                                 void* __restrict__ Cv,
                                                 const float* __restrict__ bias,
                                                 int M, int N, int K, int lda,
                                                 u16* __restrict__ vt) {
    __shared__ __align__(16) u16 As[BM * BKA];   // 16 KB
    __shared__ __align__(16) u16 Ws[BN * BKA];   // 16 KB

    const int tid  = threadIdx.x;
    const int lane = tid & 63;
    const int w    = tid >> 6;
    const int wr   = w >> 1;
    const int wc   = w & 1;
    const int quad = lane >> 4;
    const int l16  = lane & 15;

    const int row0 = blockIdx.y * BM;
    const int col0 = blockIdx.x * BN;

    const int srow = w * 8 + (lane >> 3);
    const int gc   = (lane & 7) ^ (lane >> 3);

    const u16* gA[4]; const u16* gW[4]; u16* lA[4]; u16* lW[4];
#pragma unroll
    for (int p = 0; p < 4; p++) {
        gA[p] = A + (size_t)(row0 + p * 32 + srow) * lda + gc * 8;
        gW[p] = W + (size_t)(col0 + p * 32 + srow) * K  + gc * 8;
        lA[p] = &As[(p * 32 + w * 8) * BKA];
        lW[p] = &Ws[(p * 32 + w * 8) * BKA];
    }

    const int cr0 = (quad ^ (l16 & 7)) * 8;

    f32x4 acc[4][4] = {};

    for (int k0 = 0; k0 < K; k0 += BKA) {
        __syncthreads();
#pragma unroll
        for (int p = 0; p < 4; p++) {
            gl16(gA[p] + k0, lA[p]);
            gl16(gW[p] + k0, lW[p]);
        }
        __syncthreads();

#pragma unroll
        for (int ks = 0; ks < 2; ks++) {
            const int cc = cr0 ^ (ks * 32);
            short8 af[4], bfr[4];
#pragma unroll
            for (int i = 0; i < 4; i++)
                af[i] = *reinterpret_cast<const short8*>(&As[(wr * 64 + i * 16 + l16) * BKA + cc]);
#pragma unroll
            for (int j = 0; j < 4; j++)
                bfr[j] = *reinterpret_cast<const short8*>(&Ws[(wc * 64 + j * 16 + l16) * BKA + cc]);
#pragma unroll
            for (int i = 0; i < 4; i++)
#pragma unroll
                for (int j = 0; j < 4; j++)
                    acc[i][j] = __builtin_amdgcn_mfma_f32_16x16x32_bf16(af[i], bfr[j], acc[i][j], 0, 0, 0);
        }
    }

    if (vt != nullptr && col0 >= 2048) {
        const int b = row0 >> 10;
#pragma unroll
        for (int j = 0; j < 4; j++) {
            const int hd = col0 - 2048 + wc * 64 + j * 16 + l16;
            u16* dstc = vt + (size_t)(b * 1024 + hd) * 1024 + (row0 & 1023) + wr * 64;
#pragma unroll
            for (int i = 0; i < 4; i++) {
                const int t0 = i * 16 + quad * 4;
                u16 pk[4];
#pragma unroll
                for (int r = 0; r < 4; r++) pk[r] = f2bf(acc[i][j][r]);
                *reinterpret_cast<uint2*>(dstc + t0) = *reinterpret_cast<uint2*>(pk);
            }
        }
    } else {
#pragma unroll
        for (int j = 0; j < 4; j++) {
            const int col = col0 + wc * 64 + j * 16 + l16;
            const float bval = bias ? bias[col] : 0.0f;
#pragma unroll
            for (int i = 0; i < 4; i++) {
#pragma unroll
                for (int r = 0; r < 4; r++) {
                    const int row = row0 + wr * 64 + i * 16 + quad * 4 + r;
                    if (CF32) ((float*)Cv)[(size_t)row * N + col] = acc[i][j][r] + bval;
                    else      ((u16*)Cv)[(size_t)row * N + col]  = f2bf(acc[i][j][r] + bval);
                }
            }
        }
    }
}

// ============================================================
// fallback GEMM (fp32 staging paths, known-good R2)
// ============================================================
template<bool AF32, bool WF32, bool CF32>
__global__ __launch_bounds__(256) void gemm_bt(const void* __restrict__ Av,
                                               const void* __restrict__ Wv,
                                               void* __restrict__ Cv,
                                               const float* __restrict__ bias,
                                               int M, int N, int K, int lda) {
    __shared__ __align__(16) u16 As[BM * BK];
    __shared__ __align__(16) u16 Ws[BN * BK];

    const int tid  = threadIdx.x;
    const int lane = tid & 63;
    const int wave = tid >> 6;
    const int wr   = wave >> 1;
    const int wc   = wave & 1;
    const int quad = lane >> 4;
    const int l16  = lane & 15;

    const int row0 = blockIdx.y * BM;
    const int col0 = blockIdx.x * BN;

    const int sr = tid >> 2;
    const int sc = (tid & 3) * 8;

    f32x4 acc[4][4] = {};

    for (int k0 = 0; k0 < K; k0 += BK) {
        __syncthreads();
        if (AF32) {
            const float* A = (const float*)Av;
            *reinterpret_cast<uint4*>(&As[(sr)      * BK + sc]) = cvt8(&A[(size_t)(row0 + sr)      * lda + k0 + sc]);
            *reinterpret_cast<uint4*>(&As[(sr + 64) * BK + sc]) = cvt8(&A[(size_t)(row0 + sr + 64) * lda + k0 + sc]);
        } else {
            const u16* A = (const u16*)Av;
            *reinterpret_cast<uint4*>(&As[(sr)      * BK + sc]) =
                *reinterpret_cast<const uint4*>(&A[(size_t)(row0 + sr)      * lda + k0 + sc]);
            *reinterpret_cast<uint4*>(&As[(sr + 64) * BK + sc]) =
                *reinterpret_cast<const uint4*>(&A[(size_t)(row0 + sr + 64) * lda + k0 + sc]);
        }
        if (WF32) {
            const float* W = (const float*)Wv;
            *reinterpret_cast<uint4*>(&Ws[(sr)      * BK + sc]) = cvt8(&W[(size_t)(col0 + sr)      * K + k0 + sc]);
            *reinterpret_cast<uint4*>(&Ws[(sr + 64) * BK + sc]) = cvt8(&W[(size_t)(col0 + sr + 64) * K + k0 + sc]);
        } else {
            const u16* W = (const u16*)Wv;
            *reinterpret_cast<uint4*>(&Ws[(sr)      * BK + sc]) =
                *reinterpret_cast<const uint4*>(&W[(size_t)(col0 + sr)      * K + k0 + sc]);
            *reinterpret_cast<uint4*>(&Ws[(sr + 64) * BK + sc]) =
                *reinterpret_cast<const uint4*>(&W[(size_t)(col0 + sr + 64) * K + k0 + sc]);
        }
        __syncthreads();

        short8 af[4], bfr[4];
#pragma unroll
        for (int i = 0; i < 4; i++)
            af[i] = *reinterpret_cast<const short8*>(&As[(wr * 64 + i * 16 + l16) * BK + quad * 8]);
#pragma unroll
        for (int j = 0; j < 4; j++)
            bfr[j] = *reinterpret_cast<const short8*>(&Ws[(wc * 64 + j * 16 + l16) * BK + quad * 8]);

#pragma unroll
        for (int i = 0; i < 4; i++)
#pragma unroll
            for (int j = 0; j < 4; j++)
                acc[i][j] = __builtin_amdgcn_mfma_f32_16x16x32_bf16(af[i], bfr[j], acc[i][j], 0, 0, 0);
    }

#pragma unroll
    for (int j = 0; j < 4; j++) {
        const int col = col0 + wc * 64 + j * 16 + l16;
        const float bval = bias ? bias[col] : 0.0f;
#pragma unroll
        for (int i = 0; i < 4; i++) {
#pragma unroll
            for (int r = 0; r < 4; r++) {
                const int row = row0 + wr * 64 + i * 16 + quad * 4 + r;
                if (CF32) ((float*)Cv)[(size_t)row * N + col] = acc[i][j][r] + bval;
                else      ((u16*)Cv)[(size_t)row * N + col]  = f2bf(acc[i][j][r] + bval);
            }
        }
    }
}

// ============================================================
// V transpose (fallback tiers only): qkv v-section -> Vt[b][h][dh][t]
// ============================================================
__global__ __launch_bounds__(256) void vtrans_kernel(const u16* __restrict__ qkv,
                                                     u16* __restrict__ vt) {
    const int bid = blockIdx.x;
    const int tt = bid & 15, h = (bid >> 4) & 15, b = bid >> 8;
    const int t0 = tt * 64;
    __shared__ __align__(16) u16 tile[64 * 72];
    const int tr = threadIdx.x >> 2, tc = (threadIdx.x & 3) * 16;
    const u16* src = qkv + (size_t)(b * 1024 + t0 + tr) * 3072 + 2048 + h * 64 + tc;
    *reinterpret_cast<uint4*>(&tile[tr * 72 + tc])     = *reinterpret_cast<const uint4*>(src);
    *reinterpret_cast<uint4*>(&tile[tr * 72 + tc + 8]) = *reinterpret_cast<const uint4*>(src + 8);
    __syncthreads();
    const int dh = tr, t1 = tc;
    __align__(16) u16 buf[16];
#pragma unroll
    for (int i = 0; i < 16; i++) buf[i] = tile[(t1 + i) * 72 + dh];
    u16* dst = vt + ((size_t)(b * 16 + h) * 64 + dh) * 1024 + t0 + t1;
    *reinterpret_cast<uint4*>(dst)     = *reinterpret_cast<uint4*>(&buf[0]);
    *reinterpret_cast<uint4*>(dst + 8) = *reinterpret_cast<uint4*>(&buf[8]);
}

// ============================================================
// MFMA flash attention (S^T formulation) — R5 staging restored.
// NOTE (R6 lesson): global_load_lds regressed here (+9 µs).
// ============================================================
#define SK 72

__global__ __launch_bounds__(256) void fattn_kernel(u16* __restrict__ qkv,
                                                    const u16* __restrict__ vt) {
    __shared__ __align__(16) u16 Ks[64 * SK];
    __shared__ __align__(16) u16 Vs[64 * SK];
    __shared__ __align__(16) u16 Ps[4][32 * SK];
    __shared__ __align__(16) float aS[4][32];

    const int tid  = threadIdx.x;
    const int lane = tid & 63;
    const int w    = tid >> 6;
    const int quad = lane >> 4;
    const int l16  = lane & 15;

    const int bid = blockIdx.x;
    const int qt  = 7 - (bid >> 7);
    const int bh  = bid & 127;
    const int b   = bh >> 4;
    const int h   = bh & 15;

    u16* qb        = qkv + (size_t)b * 1024 * 3072;
    const u16* vtb = vt + (size_t)bh * 64 * 1024;

    const int qrow0 = qt * 128 + w * 32;

    short8 qf[2][2];
#pragma unroll
    for (int mj = 0; mj < 2; mj++)
#pragma unroll
        for (int ks = 0; ks < 2; ks++) {
            const u16* src = qb + (size_t)(qrow0 + mj * 16 + l16) * 3072 + 1024 + h * 64 + ks * 32 + quad * 8;
            __align__(16) u16 tmp[8];
            *reinterpret_cast<uint4*>(tmp) = *reinterpret_cast<const uint4*>(src);
#pragma unroll
            for (int e = 0; e < 8; e++) tmp[e] = f2bf(bf2f(tmp[e]) * 0.125f);
            qf[mj][ks] = *reinterpret_cast<short8*>(tmp);
        }

    f32x4 oa[2][4] = {};
    float m_run[2] = {-1e30f, -1e30f};
    float l_run[2] = {0.f, 0.f};

    const int jtmax = 2 * qt + 1;
    for (int jt = 0; jt <= jtmax; jt++) {
        const int j0 = jt * 64;
        __syncthreads();
        {
            const int sr = tid >> 2, sc = (tid & 3) * 8;
            const u16* kg = qb + (size_t)(j0 + sr) * 3072 + h * 64;
            *reinterpret_cast<uint4*>(&Ks[sr * SK + sc])      = *reinterpret_cast<const uint4*>(kg + sc);
            *reinterpret_cast<uint4*>(&Ks[sr * SK + sc + 32]) = *reinterpret_cast<const uint4*>(kg + sc + 32);
            const u16* vg = vtb + (size_t)sr * 1024 + j0;
            *reinterpret_cast<uint4*>(&Vs[sr * SK + sc])      = *reinterpret_cast<const uint4*>(vg + sc);
            *reinterpret_cast<uint4*>(&Vs[sr * SK + sc + 32]) = *reinterpret_cast<const uint4*>(vg + sc + 32);
        }
        __syncthreads();

        if (j0 > qrow0 + 31) continue;

        f32x4 s[4][2] = {};
#pragma unroll
        for (int ks = 0; ks < 2; ks++) {
            short8 kf[4];
#pragma unroll
            for (int ti = 0; ti < 4; ti++)
                kf[ti] = *reinterpret_cast<const short8*>(&Ks[(ti * 16 + l16) * SK + ks * 32 + quad * 8]);
#pragma unroll
            for (int ti = 0; ti < 4; ti++)
#pragma unroll
                for (int mj = 0; mj < 2; mj++)
                    s[ti][mj] = __builtin_amdgcn_mfma_f32_16x16x32_bf16(kf[ti], qf[mj][ks], s[ti][mj], 0, 0, 0);
        }

        const bool need_mask = (j0 + 63 > qrow0);
#pragma unroll
        for (int mj = 0; mj < 2; mj++) {
            const int mg = qrow0 + mj * 16 + l16;
            if (need_mask) {
#pragma unroll
                for (int ti = 0; ti < 4; ti++)
#pragma unroll
                    for (int r = 0; r < 4; r++)
                        if (j0 + ti * 16 + quad * 4 + r > mg) s[ti][mj][r] = -1e30f;
            }
            float mt = -1e30f;
#pragma unroll
            for (int ti = 0; ti < 4; ti++)
#pragma unroll
                for (int r = 0; r < 4; r++) mt = fmaxf(mt, s[ti][mj][r]);
            mt = fmaxf(mt, __shfl_xor(mt, 16));
            mt = fmaxf(mt, __shfl_xor(mt, 32));
            const float mn    = fmaxf(m_run[mj], mt);
            const float alpha = __expf(m_run[mj] - mn);
            m_run[mj] = mn;
            float ls = 0.f;
#pragma unroll
            for (int ti = 0; ti < 4; ti++)
#pragma unroll
                for (int r = 0; r < 4; r++) {
                    const float p = __expf(s[ti][mj][r] - mn);
                    s[ti][mj][r] = p;
                    ls += p;
                }
            ls += __shfl_xor(ls, 16);
            ls += __shfl_xor(ls, 32);
            l_run[mj] = l_run[mj] * alpha + ls;
            if (lane < 16) aS[w][mj * 16 + l16] = alpha;
#pragma unroll
            for (int ti = 0; ti < 4; ti++) {
                uint2 pk;
                pk.x = (unsigned)f2bf(s[ti][mj][0]) | ((unsigned)f2bf(s[ti][mj][1]) << 16);
                pk.y = (unsigned)f2bf(s[ti][mj][2]) | ((unsigned)f2bf(s[ti][mj][3]) << 16);
                *reinterpret_cast<uint2*>(&Ps[w][(mj * 16 + l16) * SK + ti * 16 + quad * 4]) = pk;
            }
        }

#pragma unroll
        for (int mi = 0; mi < 2; mi++) {
            const f32x4 av = *reinterpret_cast<const f32x4*>(&aS[w][mi * 16 + quad * 4]);
#pragma unroll
            for (int nd = 0; nd < 4; nd++)
#pragma unroll
                for (int r = 0; r < 4; r++) oa[mi][nd][r] *= av[r];
        }

#pragma unroll
        for (int ks = 0; ks < 2; ks++) {
            short8 pf[2], vf[4];
#pragma unroll
            for (int mi = 0; mi < 2; mi++)
                pf[mi] = *reinterpret_cast<const short8*>(&Ps[w][(mi * 16 + l16) * SK + ks * 32 + quad * 8]);
#pragma unroll
            for (int nd = 0; nd < 4; nd++)
                vf[nd] = *reinterpret_cast<const short8*>(&Vs[(nd * 16 + l16) * SK + ks * 32 + quad * 8]);
#pragma unroll
            for (int mi = 0; mi < 2; mi++)
#pragma unroll
                for (int nd = 0; nd < 4; nd++)
                    oa[mi][nd] = __builtin_amdgcn_mfma_f32_16x16x32_bf16(pf[mi], vf[nd], oa[mi][nd], 0, 0, 0);
        }
    }

    if (lane < 16) { aS[w][l16] = 1.f / l_run[0]; aS[w][16 + l16] = 1.f / l_run[1]; }
#pragma unroll
    for (int mi = 0; mi < 2; mi++) {
        const f32x4 iv = *reinterpret_cast<const f32x4*>(&aS[w][mi * 16 + quad * 4]);
#pragma unroll
        for (int nd = 0; nd < 4; nd++)
#pragma unroll
            for (int r = 0; r < 4; r++) {
                const int row = qrow0 + mi * 16 + quad * 4 + r;
                qb[(size_t)row * 3072 + 1024 + h * 64 + nd * 16 + l16] = f2bf(oa[mi][nd][r] * iv[r]);
            }
    }
}

// ============================================================
// tier-3 fallback: scalar flash attention (known-good from R1)
// ============================================================
__global__ __launch_bounds__(256) void attn_kernel(u16* __restrict__ qkv) {
    const int g  = blockIdx.x * 256 + threadIdx.x;
    const int q  = g & 1023;
    const int bh = g >> 10;
    const int b  = bh >> 4;
    const int h  = bh & 15;
    const size_t base = (size_t)b * 1024 * 3072 + (size_t)h * 64;
    float qv[64];
    {
        const uint4* q4 = reinterpret_cast<const uint4*>(qkv + base + (size_t)q * 3072 + 1024);
#pragma unroll
        for (int c = 0; c < 8; c++) {
            uint4 t = q4[c];
            qv[c*8+0]=bf_lo(t.x); qv[c*8+1]=bf_hi(t.x); qv[c*8+2]=bf_lo(t.y); qv[c*8+3]=bf_hi(t.y);
            qv[c*8+4]=bf_lo(t.z); qv[c*8+5]=bf_hi(t.z); qv[c*8+6]=bf_lo(t.w); qv[c*8+7]=bf_hi(t.w);
        }
    }
    float o[64];
#pragma unroll
    for (int i = 0; i < 64; i++) o[i] = 0.0f;
    float m = -1e30f, l = 0.0f;
    const int jmax = q | 63;
    for (int j = 0; j <= jmax; j++) {
        const uint4* k4 = reinterpret_cast<const uint4*>(qkv + base + (size_t)j * 3072);
        float s = 0.0f;
#pragma unroll
        for (int c = 0; c < 8; c++) {
            uint4 t = k4[c];
            s += qv[c*8+0]*bf_lo(t.x)+qv[c*8+1]*bf_hi(t.x)+qv[c*8+2]*bf_lo(t.y)+qv[c*8+3]*bf_hi(t.y)
               + qv[c*8+4]*bf_lo(t.z)+qv[c*8+5]*bf_hi(t.z)+qv[c*8+6]*bf_lo(t.w)+qv[c*8+7]*bf_hi(t.w);
        }
        s *= 0.125f;
        const bool act = (j <= q);
        if (!act) s = -1e30f;
        const float mn = fmaxf(m, s);
        const float alpha = __expf(m - mn);
        float p = __expf(s - mn);
        if (!act) p = 0.0f;
        l = l * alpha + p;
        const uint4* v4 = reinterpret_cast<const uint4*>(qkv + base + (size_t)j * 3072 + 2048);
#pragma unroll
        for (int c = 0; c < 8; c++) {
            uint4 t = v4[c];
            o[c*8+0]=o[c*8+0]*alpha+p*bf_lo(t.x); o[c*8+1]=o[c*8+1]*alpha+p*bf_hi(t.x);
            o[c*8+2]=o[c*8+2]*alpha+p*bf_lo(t.y); o[c*8+3]=o[c*8+3]*alpha+p*bf_hi(t.y);
            o[c*8+4]=o[c*8+4]*alpha+p*bf_lo(t.z); o[c*8+5]=o[c*8+5]*alpha+p*bf_hi(t.z);
            o[c*8+6]=o[c*8+6]*alpha+p*bf_lo(t.w); o[c*8+7]=o[c*8+7]*alpha+p*bf_hi(t.w);
        }
        m = mn;
    }
    const float inv = 1.0f / l;
    u16* yrow = qkv + base + (size_t)q * 3072 + 1024;
#pragma unroll
    for (int i = 0; i < 64; i++) yrow[i] = f2bf(o[i] * inv);
}

// ============================================================
extern "C" void kernel_launch(void* const* d_in, const int* in_sizes, int n_in,
                              void* d_out, int out_size, void* d_ws, size_t ws_size,
                              hipStream_t stream) {
    const float* x      = (const float*)d_in[0];   // [8192, 1024]
    const float* w_attn = (const float*)d_in[1];   // [3072, 1024]
    const float* w_proj = (const float*)d_in[2];   // [1024, 1024]
    const float* b_proj = (const float*)d_in[3];   // [1024]
    float* out = (float*)d_out;

    const int M = 8192, K = 1024;
    const size_t QKV = (size_t)8192 * 3072;        // 50.3 MB bf16
    const size_t VT  = (size_t)8 * 16 * 64 * 1024; // 16.8 MB bf16

    u16* qkv = (u16*)d_ws;
    u16* vtb = qkv + QKV;
    u16* xb  = vtb + VT;
    u16* wab = xb + (size_t)8192 * 1024;
    u16* wpb = wab + (size_t)3072 * 1024;

    const size_t need_full = (QKV + VT + (size_t)8192*1024 + (size_t)3072*1024 + (size_t)1024*1024) * 2;
    const size_t need_mid  = (QKV + VT) * 2;

    if (ws_size >= need_full) {
        // one fused convert: dest regions xb|wab|wpb are contiguous
        cvt3_kernel<<<6144, 256, 0, stream>>>(x, 8192 * 1024 / 8,
                                              w_attn, 3072 * 1024 / 8,
                                              w_proj, 1024 * 1024 / 8, xb);
        // qkv-gemm (m201-faithful 256x256 8-phase); v-cols transposed into vtb
        gemm256<false><<<dim3(12, 32), 512, 0, stream>>>(xb, wab, qkv, nullptr, M, 3072, K, K, vtb);
        fattn_kernel<<<1024, 256, 0, stream>>>(qkv, vtb);
        gemm_bt_a<true><<<dim3(8, 64), 256, 0, stream>>>(qkv + 1024, wpb, out, b_proj, M, 1024, K, 3072, nullptr);
    } else if (ws_size >= need_mid) {
        gemm_bt<true, true, false><<<dim3(24, 64), 256, 0, stream>>>(x, w_attn, qkv, nullptr, M, 3072, K, K);
        vtrans_kernel<<<2048, 256, 0, stream>>>(qkv, vtb);
        fattn_kernel<<<1024, 256, 0, stream>>>(qkv, vtb);
        gemm_bt<false, true, true><<<dim3(8, 64), 256, 0, stream>>>(qkv + 1024, w_proj, out, b_proj, M, 1024, K, 3072);
    } else {
        gemm_bt<true, true, false><<<dim3(24, 64), 256, 0, stream>>>(x, w_attn, qkv, nullptr, M, 3072, K, K);
        attn_kernel<<<512, 256, 0, stream>>>(qkv);
        gemm_bt<false, true, true><<<dim3(8, 64), 256, 0, stream>>>(qkv + 1024, w_proj, out, b_proj, M, 1024, K, 3072);
    }
}

// Round 4
// 229.597 us; speedup vs baseline: 1.1392x; 1.1392x over previous
//
#include <hip/hip_runtime.h>
#include <stdint.h>

typedef unsigned short u16;
typedef __attribute__((ext_vector_type(8))) short short8;   // 8 bf16 in 4 VGPRs
typedef __attribute__((ext_vector_type(4))) float f32x4;

// ---------- bf16 helpers ----------
__device__ __forceinline__ float bf2f(u16 u) {
    union { unsigned u; float f; } x; x.u = ((unsigned)u) << 16; return x.f;
}
__device__ __forceinline__ float bf_lo(unsigned w) {
    union { unsigned u; float f; } x; x.u = w << 16; return x.f;
}
__device__ __forceinline__ float bf_hi(unsigned w) {
    union { unsigned u; float f; } x; x.u = w & 0xffff0000u; return x.f;
}
__device__ __forceinline__ u16 f2bf(float f) {   // round-to-nearest-even
    union { float f; unsigned u; } x; x.f = f;
    unsigned r = x.u + 0x7fffu + ((x.u >> 16) & 1u);
    return (u16)(r >> 16);
}
__device__ __forceinline__ uint4 cvt8(const float* p) {
    float4 a = *reinterpret_cast<const float4*>(p);
    float4 b = *reinterpret_cast<const float4*>(p + 4);
    uint4 r;
    r.x = (unsigned)f2bf(a.x) | ((unsigned)f2bf(a.y) << 16);
    r.y = (unsigned)f2bf(a.z) | ((unsigned)f2bf(a.w) << 16);
    r.z = (unsigned)f2bf(b.x) | ((unsigned)f2bf(b.y) << 16);
    r.w = (unsigned)f2bf(b.z) | ((unsigned)f2bf(b.w) << 16);
    return r;
}

// async global -> LDS, 16 bytes per lane (lds dest = wave-uniform base + lane*16)
__device__ __forceinline__ void gl16(const u16* g, u16* l) {
    __builtin_amdgcn_global_load_lds(
        (const __attribute__((address_space(1))) void*)g,
        (__attribute__((address_space(3))) void*)l, 16, 0, 0);
}

// ---------- fp32 -> bf16 bulk converts ----------
__global__ __launch_bounds__(256) void cvt_kernel(const float* __restrict__ in,
                                                  u16* __restrict__ out, int n8) {
    int i = blockIdx.x * 256 + threadIdx.x;
    if (i < n8) *reinterpret_cast<uint4*>(&out[(size_t)i * 8]) = cvt8(&in[(size_t)i * 8]);
}

// fused 3-array convert into one contiguous bf16 region
__global__ __launch_bounds__(256) void cvt3_kernel(const float* __restrict__ a, int na8,
                                                   const float* __restrict__ b, int nb8,
                                                   const float* __restrict__ c, int nc8,
                                                   u16* __restrict__ dst) {
    int i = blockIdx.x * 256 + threadIdx.x;
    const float* src; int off;
    if (i < na8)            { src = a; off = i; }
    else if (i < na8 + nb8) { src = b; off = i - na8; }
    else if (i < na8 + nb8 + nc8) { src = c; off = i - na8 - nb8; }
    else return;
    *reinterpret_cast<uint4*>(&dst[(size_t)i * 8]) = cvt8(&src[(size_t)off * 8]);
}

#define BM 128
#define BN 128
#define BK 32
#define BKA 64

// ============================================================
// m97-class GEMM, BK=64, SINGLE-buffered — BEST KNOWN (68.5 µs / 752 TF
// on QKV shape, R1 counters: MfmaUtil 31%, 0 bank conflicts, 3 blk/CU).
// NOTE (R2/R3 lessons): phase-interleaved 8-phase variants (gemm8p 71 µs,
// m201-faithful gemm256 94 µs) BOTH lost at K=1024 — 1 blk/CU lockstep
// barriers kill the inter-block overlap that carries this structure.
// Do not re-attempt counted-vmcnt pipelines on this shape.
// global_load_lds width=16 staging; XOR swizzle: LDS slot (row r, chunk c)
// holds global chunk c ^ (r&7) -> 0 bank conflicts (measured).
// If vt != nullptr, blocks with col0 >= 2048 write transposed V.
// ============================================================
template<bool CF32>
__global__ __launch_bounds__(256) void gemm_bt_a(const u16* __restrict__ A,
                                                 const u16* __restrict__ W,
                                                 void* __restrict__ Cv,
                                                 const float* __restrict__ bias,
                                                 int M, int N, int K, int lda,
                                                 u16* __restrict__ vt) {
    __shared__ __align__(16) u16 As[BM * BKA];   // 16 KB
    __shared__ __align__(16) u16 Ws[BN * BKA];   // 16 KB

    const int tid  = threadIdx.x;
    const int lane = tid & 63;
    const int w    = tid >> 6;
    const int wr   = w >> 1;
    const int wc   = w & 1;
    const int quad = lane >> 4;
    const int l16  = lane & 15;

    const int row0 = blockIdx.y * BM;
    const int col0 = blockIdx.x * BN;

    const int srow = w * 8 + (lane >> 3);
    const int gc   = (lane & 7) ^ (lane >> 3);

    const u16* gA[4]; const u16* gW[4]; u16* lA[4]; u16* lW[4];
#pragma unroll
    for (int p = 0; p < 4; p++) {
        gA[p] = A + (size_t)(row0 + p * 32 + srow) * lda + gc * 8;
        gW[p] = W + (size_t)(col0 + p * 32 + srow) * K  + gc * 8;
        lA[p] = &As[(p * 32 + w * 8) * BKA];
        lW[p] = &Ws[(p * 32 + w * 8) * BKA];
    }

    const int cr0 = (quad ^ (l16 & 7)) * 8;

    f32x4 acc[4][4] = {};

    for (int k0 = 0; k0 < K; k0 += BKA) {
        __syncthreads();
#pragma unroll
        for (int p = 0; p < 4; p++) {
            gl16(gA[p] + k0, lA[p]);
            gl16(gW[p] + k0, lW[p]);
        }
        __syncthreads();   // vmcnt drain before barrier (m97 structure)

#pragma unroll
        for (int ks = 0; ks < 2; ks++) {
            const int cc = cr0 ^ (ks * 32);
            short8 af[4], bfr[4];
#pragma unroll
            for (int i = 0; i < 4; i++)
                af[i] = *reinterpret_cast<const short8*>(&As[(wr * 64 + i * 16 + l16) * BKA + cc]);
#pragma unroll
            for (int j = 0; j < 4; j++)
                bfr[j] = *reinterpret_cast<const short8*>(&Ws[(wc * 64 + j * 16 + l16) * BKA + cc]);
#pragma unroll
            for (int i = 0; i < 4; i++)
#pragma unroll
                for (int j = 0; j < 4; j++)
                    acc[i][j] = __builtin_amdgcn_mfma_f32_16x16x32_bf16(af[i], bfr[j], acc[i][j], 0, 0, 0);
        }
    }

    // epilogue: C/D layout col=lane&15, row=quad*4+reg  [verified m89/m91]
    if (vt != nullptr && col0 >= 2048) {
        // fused V-transpose: 4 consecutive t per lane -> one 8B store
        const int b = row0 >> 10;
#pragma unroll
        for (int j = 0; j < 4; j++) {
            const int hd = col0 - 2048 + wc * 64 + j * 16 + l16;   // h*64+dh
            u16* dstc = vt + (size_t)(b * 1024 + hd) * 1024 + (row0 & 1023) + wr * 64;
#pragma unroll
            for (int i = 0; i < 4; i++) {
                const int t0 = i * 16 + quad * 4;
                u16 pk[4];
#pragma unroll
                for (int r = 0; r < 4; r++) pk[r] = f2bf(acc[i][j][r]);
                *reinterpret_cast<uint2*>(dstc + t0) = *reinterpret_cast<uint2*>(pk);
            }
        }
    } else {
#pragma unroll
        for (int j = 0; j < 4; j++) {
            const int col = col0 + wc * 64 + j * 16 + l16;
            const float bval = bias ? bias[col] : 0.0f;
#pragma unroll
            for (int i = 0; i < 4; i++) {
#pragma unroll
                for (int r = 0; r < 4; r++) {
                    const int row = row0 + wr * 64 + i * 16 + quad * 4 + r;
                    if (CF32) ((float*)Cv)[(size_t)row * N + col] = acc[i][j][r] + bval;
                    else      ((u16*)Cv)[(size_t)row * N + col]  = f2bf(acc[i][j][r] + bval);
                }
            }
        }
    }
}

// ============================================================
// fallback GEMM (fp32 staging paths, known-good R2)
// ============================================================
template<bool AF32, bool WF32, bool CF32>
__global__ __launch_bounds__(256) void gemm_bt(const void* __restrict__ Av,
                                               const void* __restrict__ Wv,
                                               void* __restrict__ Cv,
                                               const float* __restrict__ bias,
                                               int M, int N, int K, int lda) {
    __shared__ __align__(16) u16 As[BM * BK];
    __shared__ __align__(16) u16 Ws[BN * BK];

    const int tid  = threadIdx.x;
    const int lane = tid & 63;
    const int wave = tid >> 6;
    const int wr   = wave >> 1;
    const int wc   = wave & 1;
    const int quad = lane >> 4;
    const int l16  = lane & 15;

    const int row0 = blockIdx.y * BM;
    const int col0 = blockIdx.x * BN;

    const int sr = tid >> 2;
    const int sc = (tid & 3) * 8;

    f32x4 acc[4][4] = {};

    for (int k0 = 0; k0 < K; k0 += BK) {
        __syncthreads();
        if (AF32) {
            const float* A = (const float*)Av;
            *reinterpret_cast<uint4*>(&As[(sr)      * BK + sc]) = cvt8(&A[(size_t)(row0 + sr)      * lda + k0 + sc]);
            *reinterpret_cast<uint4*>(&As[(sr + 64) * BK + sc]) = cvt8(&A[(size_t)(row0 + sr + 64) * lda + k0 + sc]);
        } else {
            const u16* A = (const u16*)Av;
            *reinterpret_cast<uint4*>(&As[(sr)      * BK + sc]) =
                *reinterpret_cast<const uint4*>(&A[(size_t)(row0 + sr)      * lda + k0 + sc]);
            *reinterpret_cast<uint4*>(&As[(sr + 64) * BK + sc]) =
                *reinterpret_cast<const uint4*>(&A[(size_t)(row0 + sr + 64) * lda + k0 + sc]);
        }
        if (WF32) {
            const float* W = (const float*)Wv;
            *reinterpret_cast<uint4*>(&Ws[(sr)      * BK + sc]) = cvt8(&W[(size_t)(col0 + sr)      * K + k0 + sc]);
            *reinterpret_cast<uint4*>(&Ws[(sr + 64) * BK + sc]) = cvt8(&W[(size_t)(col0 + sr + 64) * K + k0 + sc]);
        } else {
            const u16* W = (const u16*)Wv;
            *reinterpret_cast<uint4*>(&Ws[(sr)      * BK + sc]) =
                *reinterpret_cast<const uint4*>(&W[(size_t)(col0 + sr)      * K + k0 + sc]);
            *reinterpret_cast<uint4*>(&Ws[(sr + 64) * BK + sc]) =
                *reinterpret_cast<const uint4*>(&W[(size_t)(col0 + sr + 64) * K + k0 + sc]);
        }
        __syncthreads();

        short8 af[4], bfr[4];
#pragma unroll
        for (int i = 0; i < 4; i++)
            af[i] = *reinterpret_cast<const short8*>(&As[(wr * 64 + i * 16 + l16) * BK + quad * 8]);
#pragma unroll
        for (int j = 0; j < 4; j++)
            bfr[j] = *reinterpret_cast<const short8*>(&Ws[(wc * 64 + j * 16 + l16) * BK + quad * 8]);

#pragma unroll
        for (int i = 0; i < 4; i++)
#pragma unroll
            for (int j = 0; j < 4; j++)
                acc[i][j] = __builtin_amdgcn_mfma_f32_16x16x32_bf16(af[i], bfr[j], acc[i][j], 0, 0, 0);
    }

#pragma unroll
    for (int j = 0; j < 4; j++) {
        const int col = col0 + wc * 64 + j * 16 + l16;
        const float bval = bias ? bias[col] : 0.0f;
#pragma unroll
        for (int i = 0; i < 4; i++) {
#pragma unroll
            for (int r = 0; r < 4; r++) {
                const int row = row0 + wr * 64 + i * 16 + quad * 4 + r;
                if (CF32) ((float*)Cv)[(size_t)row * N + col] = acc[i][j][r] + bval;
                else      ((u16*)Cv)[(size_t)row * N + col]  = f2bf(acc[i][j][r] + bval);
            }
        }
    }
}

// ============================================================
// V transpose (fallback tiers only): qkv v-section -> Vt[b][h][dh][t]
// ============================================================
__global__ __launch_bounds__(256) void vtrans_kernel(const u16* __restrict__ qkv,
                                                     u16* __restrict__ vt) {
    const int bid = blockIdx.x;
    const int tt = bid & 15, h = (bid >> 4) & 15, b = bid >> 8;
    const int t0 = tt * 64;
    __shared__ __align__(16) u16 tile[64 * 72];
    const int tr = threadIdx.x >> 2, tc = (threadIdx.x & 3) * 16;
    const u16* src = qkv + (size_t)(b * 1024 + t0 + tr) * 3072 + 2048 + h * 64 + tc;
    *reinterpret_cast<uint4*>(&tile[tr * 72 + tc])     = *reinterpret_cast<const uint4*>(src);
    *reinterpret_cast<uint4*>(&tile[tr * 72 + tc + 8]) = *reinterpret_cast<const uint4*>(src + 8);
    __syncthreads();
    const int dh = tr, t1 = tc;
    __align__(16) u16 buf[16];
#pragma unroll
    for (int i = 0; i < 16; i++) buf[i] = tile[(t1 + i) * 72 + dh];
    u16* dst = vt + ((size_t)(b * 16 + h) * 64 + dh) * 1024 + t0 + t1;
    *reinterpret_cast<uint4*>(dst)     = *reinterpret_cast<uint4*>(&buf[0]);
    *reinterpret_cast<uint4*>(dst + 8) = *reinterpret_cast<uint4*>(&buf[8]);
}

// ============================================================
// MFMA flash attention (S^T formulation).
// R9 change (T14 async-STAGE split, m214 r277 +17%): K/V tile jt+1 is
// global-loaded into REGISTERS during tile jt's staging window; its
// ~300-900 cy HBM/L2 latency hides under tile jt's full QK/softmax/PV
// compute. ds_write happens at the top of the next iteration. Barrier
// count and all compute structure unchanged (no new race surface).
// NOTE (R6 lesson): global_load_lds direct regressed here (+9 µs) — the
// reg-staged split is the right async form for this kernel.
// ============================================================
#define SK 72

__global__ __launch_bounds__(256) void fattn_kernel(u16* __restrict__ qkv,
                                                    const u16* __restrict__ vt) {
    __shared__ __align__(16) u16 Ks[64 * SK];
    __shared__ __align__(16) u16 Vs[64 * SK];
    __shared__ __align__(16) u16 Ps[4][32 * SK];
    __shared__ __align__(16) float aS[4][32];

    const int tid  = threadIdx.x;
    const int lane = tid & 63;
    const int w    = tid >> 6;
    const int quad = lane >> 4;
    const int l16  = lane & 15;

    const int bid = blockIdx.x;
    const int qt  = 7 - (bid >> 7);
    const int bh  = bid & 127;
    const int b   = bh >> 4;
    const int h   = bh & 15;

    u16* qb        = qkv + (size_t)b * 1024 * 3072;
    const u16* vtb = vt + (size_t)bh * 64 * 1024;

    const int qrow0 = qt * 128 + w * 32;

    short8 qf[2][2];
#pragma unroll
    for (int mj = 0; mj < 2; mj++)
#pragma unroll
        for (int ks = 0; ks < 2; ks++) {
            const u16* src = qb + (size_t)(qrow0 + mj * 16 + l16) * 3072 + 1024 + h * 64 + ks * 32 + quad * 8;
            __align__(16) u16 tmp[8];
            *reinterpret_cast<uint4*>(tmp) = *reinterpret_cast<const uint4*>(src);
#pragma unroll
            for (int e = 0; e < 8; e++) tmp[e] = f2bf(bf2f(tmp[e]) * 0.125f);
            qf[mj][ks] = *reinterpret_cast<short8*>(tmp);
        }

    f32x4 oa[2][4] = {};
    float m_run[2] = {-1e30f, -1e30f};
    float l_run[2] = {0.f, 0.f};

    // T14: per-thread staging addresses + prologue load of tile 0 into regs
    const int sr = tid >> 2, sc = (tid & 3) * 8;
    const u16* kg_base = qb + (size_t)sr * 3072 + h * 64;   // + j0*3072
    const u16* vg_base = vtb + (size_t)sr * 1024;           // + j0

    uint4 rk0 = *reinterpret_cast<const uint4*>(kg_base + sc);
    uint4 rk1 = *reinterpret_cast<const uint4*>(kg_base + sc + 32);
    uint4 rv0 = *reinterpret_cast<const uint4*>(vg_base + sc);
    uint4 rv1 = *reinterpret_cast<const uint4*>(vg_base + sc + 32);

    const int jtmax = 2 * qt + 1;
    for (int jt = 0; jt <= jtmax; jt++) {
        const int j0 = jt * 64;
        __syncthreads();   // previous tile's Ks/Vs readers done
        *reinterpret_cast<uint4*>(&Ks[sr * SK + sc])      = rk0;
        *reinterpret_cast<uint4*>(&Ks[sr * SK + sc + 32]) = rk1;
        *reinterpret_cast<uint4*>(&Vs[sr * SK + sc])      = rv0;
        *reinterpret_cast<uint4*>(&Vs[sr * SK + sc + 32]) = rv1;
        if (jt < jtmax) {   // issue tile jt+1 loads; land during compute below
            const u16* kg = kg_base + (size_t)(j0 + 64) * 3072;
            rk0 = *reinterpret_cast<const uint4*>(kg + sc);
            rk1 = *reinterpret_cast<const uint4*>(kg + sc + 32);
            const u16* vg = vg_base + (j0 + 64);
            rv0 = *reinterpret_cast<const uint4*>(vg + sc);
            rv1 = *reinterpret_cast<const uint4*>(vg + sc + 32);
        }
        __syncthreads();   // publish Ks/Vs

        if (j0 > qrow0 + 31) continue;

        f32x4 s[4][2] = {};
#pragma unroll
        for (int ks = 0; ks < 2; ks++) {
            short8 kf[4];
#pragma unroll
            for (int ti = 0; ti < 4; ti++)
                kf[ti] = *reinterpret_cast<const short8*>(&Ks[(ti * 16 + l16) * SK + ks * 32 + quad * 8]);
#pragma unroll
            for (int ti = 0; ti < 4; ti++)
#pragma unroll
                for (int mj = 0; mj < 2; mj++)
                    s[ti][mj] = __builtin_amdgcn_mfma_f32_16x16x32_bf16(kf[ti], qf[mj][ks], s[ti][mj], 0, 0, 0);
        }

        const bool need_mask = (j0 + 63 > qrow0);
#pragma unroll
        for (int mj = 0; mj < 2; mj++) {
            const int mg = qrow0 + mj * 16 + l16;
            if (need_mask) {
#pragma unroll
                for (int ti = 0; ti < 4; ti++)
#pragma unroll
                    for (int r = 0; r < 4; r++)
                        if (j0 + ti * 16 + quad * 4 + r > mg) s[ti][mj][r] = -1e30f;
            }
            float mt = -1e30f;
#pragma unroll
            for (int ti = 0; ti < 4; ti++)
#pragma unroll
                for (int r = 0; r < 4; r++) mt = fmaxf(mt, s[ti][mj][r]);
            mt = fmaxf(mt, __shfl_xor(mt, 16));
            mt = fmaxf(mt, __shfl_xor(mt, 32));
            const float mn    = fmaxf(m_run[mj], mt);
            const float alpha = __expf(m_run[mj] - mn);
            m_run[mj] = mn;
            float ls = 0.f;
#pragma unroll
            for (int ti = 0; ti < 4; ti++)
#pragma unroll
                for (int r = 0; r < 4; r++) {
                    const float p = __expf(s[ti][mj][r] - mn);
                    s[ti][mj][r] = p;
                    ls += p;
                }
            ls += __shfl_xor(ls, 16);
            ls += __shfl_xor(ls, 32);
            l_run[mj] = l_run[mj] * alpha + ls;
            if (lane < 16) aS[w][mj * 16 + l16] = alpha;
#pragma unroll
            for (int ti = 0; ti < 4; ti++) {
                uint2 pk;
                pk.x = (unsigned)f2bf(s[ti][mj][0]) | ((unsigned)f2bf(s[ti][mj][1]) << 16);
                pk.y = (unsigned)f2bf(s[ti][mj][2]) | ((unsigned)f2bf(s[ti][mj][3]) << 16);
                *reinterpret_cast<uint2*>(&Ps[w][(mj * 16 + l16) * SK + ti * 16 + quad * 4]) = pk;
            }
        }

#pragma unroll
        for (int mi = 0; mi < 2; mi++) {
            const f32x4 av = *reinterpret_cast<const f32x4*>(&aS[w][mi * 16 + quad * 4]);
#pragma unroll
            for (int nd = 0; nd < 4; nd++)
#pragma unroll
                for (int r = 0; r < 4; r++) oa[mi][nd][r] *= av[r];
        }

#pragma unroll
        for (int ks = 0; ks < 2; ks++) {
            short8 pf[2], vf[4];
#pragma unroll
            for (int mi = 0; mi < 2; mi++)
                pf[mi] = *reinterpret_cast<const short8*>(&Ps[w][(mi * 16 + l16) * SK + ks * 32 + quad * 8]);
#pragma unroll
            for (int nd = 0; nd < 4; nd++)
                vf[nd] = *reinterpret_cast<const short8*>(&Vs[(nd * 16 + l16) * SK + ks * 32 + quad * 8]);
#pragma unroll
            for (int mi = 0; mi < 2; mi++)
#pragma unroll
                for (int nd = 0; nd < 4; nd++)
                    oa[mi][nd] = __builtin_amdgcn_mfma_f32_16x16x32_bf16(pf[mi], vf[nd], oa[mi][nd], 0, 0, 0);
        }
    }

    if (lane < 16) { aS[w][l16] = 1.f / l_run[0]; aS[w][16 + l16] = 1.f / l_run[1]; }
#pragma unroll
    for (int mi = 0; mi < 2; mi++) {
        const f32x4 iv = *reinterpret_cast<const f32x4*>(&aS[w][mi * 16 + quad * 4]);
#pragma unroll
        for (int nd = 0; nd < 4; nd++)
#pragma unroll
            for (int r = 0; r < 4; r++) {
                const int row = qrow0 + mi * 16 + quad * 4 + r;
                qb[(size_t)row * 3072 + 1024 + h * 64 + nd * 16 + l16] = f2bf(oa[mi][nd][r] * iv[r]);
            }
    }
}

// ============================================================
// tier-3 fallback: scalar flash attention (known-good from R1)
// ============================================================
__global__ __launch_bounds__(256) void attn_kernel(u16* __restrict__ qkv) {
    const int g  = blockIdx.x * 256 + threadIdx.x;
    const int q  = g & 1023;
    const int bh = g >> 10;
    const int b  = bh >> 4;
    const int h  = bh & 15;
    const size_t base = (size_t)b * 1024 * 3072 + (size_t)h * 64;
    float qv[64];
    {
        const uint4* q4 = reinterpret_cast<const uint4*>(qkv + base + (size_t)q * 3072 + 1024);
#pragma unroll
        for (int c = 0; c < 8; c++) {
            uint4 t = q4[c];
            qv[c*8+0]=bf_lo(t.x); qv[c*8+1]=bf_hi(t.x); qv[c*8+2]=bf_lo(t.y); qv[c*8+3]=bf_hi(t.y);
            qv[c*8+4]=bf_lo(t.z); qv[c*8+5]=bf_hi(t.z); qv[c*8+6]=bf_lo(t.w); qv[c*8+7]=bf_hi(t.w);
        }
    }
    float o[64];
#pragma unroll
    for (int i = 0; i < 64; i++) o[i] = 0.0f;
    float m = -1e30f, l = 0.0f;
    const int jmax = q | 63;
    for (int j = 0; j <= jmax; j++) {
        const uint4* k4 = reinterpret_cast<const uint4*>(qkv + base + (size_t)j * 3072);
        float s = 0.0f;
#pragma unroll
        for (int c = 0; c < 8; c++) {
            uint4 t = k4[c];
            s += qv[c*8+0]*bf_lo(t.x)+qv[c*8+1]*bf_hi(t.x)+qv[c*8+2]*bf_lo(t.y)+qv[c*8+3]*bf_hi(t.y)
               + qv[c*8+4]*bf_lo(t.z)+qv[c*8+5]*bf_hi(t.z)+qv[c*8+6]*bf_lo(t.w)+qv[c*8+7]*bf_hi(t.w);
        }
        s *= 0.125f;
        const bool act = (j <= q);
        if (!act) s = -1e30f;
        const float mn = fmaxf(m, s);
        const float alpha = __expf(m - mn);
        float p = __expf(s - mn);
        if (!act) p = 0.0f;
        l = l * alpha + p;
        const uint4* v4 = reinterpret_cast<const uint4*>(qkv + base + (size_t)j * 3072 + 2048);
#pragma unroll
        for (int c = 0; c < 8; c++) {
            uint4 t = v4[c];
            o[c*8+0]=o[c*8+0]*alpha+p*bf_lo(t.x); o[c*8+1]=o[c*8+1]*alpha+p*bf_hi(t.x);
            o[c*8+2]=o[c*8+2]*alpha+p*bf_lo(t.y); o[c*8+3]=o[c*8+3]*alpha+p*bf_hi(t.y);
            o[c*8+4]=o[c*8+4]*alpha+p*bf_lo(t.z); o[c*8+5]=o[c*8+5]*alpha+p*bf_hi(t.z);
            o[c*8+6]=o[c*8+6]*alpha+p*bf_lo(t.w); o[c*8+7]=o[c*8+7]*alpha+p*bf_hi(t.w);
        }
        m = mn;
    }
    const float inv = 1.0f / l;
    u16* yrow = qkv + base + (size_t)q * 3072 + 1024;
#pragma unroll
    for (int i = 0; i < 64; i++) yrow[i] = f2bf(o[i] * inv);
}

// ============================================================
extern "C" void kernel_launch(void* const* d_in, const int* in_sizes, int n_in,
                              void* d_out, int out_size, void* d_ws, size_t ws_size,
                              hipStream_t stream) {
    const float* x      = (const float*)d_in[0];   // [8192, 1024]
    const float* w_attn = (const float*)d_in[1];   // [3072, 1024]
    const float* w_proj = (const float*)d_in[2];   // [1024, 1024]
    const float* b_proj = (const float*)d_in[3];   // [1024]
    float* out = (float*)d_out;

    const int M = 8192, K = 1024;
    const size_t QKV = (size_t)8192 * 3072;        // 50.3 MB bf16
    const size_t VT  = (size_t)8 * 16 * 64 * 1024; // 16.8 MB bf16

    u16* qkv = (u16*)d_ws;
    u16* vtb = qkv + QKV;
    u16* xb  = vtb + VT;
    u16* wab = xb + (size_t)8192 * 1024;
    u16* wpb = wab + (size_t)3072 * 1024;

    const size_t need_full = (QKV + VT + (size_t)8192*1024 + (size_t)3072*1024 + (size_t)1024*1024) * 2;
    const size_t need_mid  = (QKV + VT) * 2;

    if (ws_size >= need_full) {
        // one fused convert: dest regions xb|wab|wpb are contiguous
        cvt3_kernel<<<6144, 256, 0, stream>>>(x, 8192 * 1024 / 8,
                                              w_attn, 3072 * 1024 / 8,
                                              w_proj, 1024 * 1024 / 8, xb);
        // qkv-gemm; v-columns written transposed straight into vtb
        gemm_bt_a<false><<<dim3(24, 64), 256, 0, stream>>>(xb, wab, qkv, nullptr, M, 3072, K, K, vtb);
        fattn_kernel<<<1024, 256, 0, stream>>>(qkv, vtb);
        gemm_bt_a<true><<<dim3(8, 64), 256, 0, stream>>>(qkv + 1024, wpb, out, b_proj, M, 1024, K, 3072, nullptr);
    } else if (ws_size >= need_mid) {
        gemm_bt<true, true, false><<<dim3(24, 64), 256, 0, stream>>>(x, w_attn, qkv, nullptr, M, 3072, K, K);
        vtrans_kernel<<<2048, 256, 0, stream>>>(qkv, vtb);
        fattn_kernel<<<1024, 256, 0, stream>>>(qkv, vtb);
        gemm_bt<false, true, true><<<dim3(8, 64), 256, 0, stream>>>(qkv + 1024, w_proj, out, b_proj, M, 1024, K, 3072);
    } else {
        gemm_bt<true, true, false><<<dim3(24, 64), 256, 0, stream>>>(x, w_attn, qkv, nullptr, M, 3072, K, K);
        attn_kernel<<<512, 256, 0, stream>>>(qkv);
        gemm_bt<false, true, true><<<dim3(8, 64), 256, 0, stream>>>(qkv + 1024, w_proj, out, b_proj, M, 1024, K, 3072);
    }
}